// Round 1
// baseline (316.598 us; speedup 1.0000x reference)
//
#include <hip/hip_runtime.h>

#define EPS_ 1e-8f

// sizes: B=16, N=2048, D=128, NS=8, H=128, steps=4
// ws offsets (floats)
constexpr int OFF_K     = 0;                       // 16*2048*128 = 4194304
constexpr int OFF_WQT   = 4194304;                 // 16384
constexpr int OFF_WKT   = OFF_WQT  + 16384;
constexpr int OFF_WIHT  = OFF_WKT  + 16384;        // 49152
constexpr int OFF_WHHT  = OFF_WIHT + 49152;        // 49152
constexpr int OFF_WM1T  = OFF_WHHT + 49152;        // 16384
constexpr int OFF_WM2T  = OFF_WM1T + 16384;        // 16384
constexpr int OFF_WO1T  = OFF_WM2T + 16384;        // 65536
constexpr int OFF_WO2T  = OFF_WO1T + 65536;        // 32768
constexpr int OFF_SLOTS = OFF_WO2T + 32768;        // 32768
constexpr int OFF_PI    = OFF_SLOTS+ 32768;        // 128
constexpr int OFF_MUS   = OFF_PI   + 128;          // 16384
constexpr int OFF_QMU   = OFF_MUS  + 16384;        // 16384
constexpr int OFF_IVAR  = OFF_QMU  + 16384;        // 16384
constexpr int OFF_UN    = OFF_IVAR + 16384;        // 16*16*8*128 = 262144
constexpr int OFF_S2    = OFF_UN   + 262144;       // 262144
constexpr int OFF_DEN   = OFF_S2   + 262144;       // 2048

// ---------------------------------------------------------------------------
// init: transpose all weights into ws (coalesced matvec reads later),
// init slots = mu + exp(logsigma)*noise, pi = 1/NS
__global__ __launch_bounds__(256) void init_kernel(
    const float* __restrict__ Wq,  const float* __restrict__ Wk,
    const float* __restrict__ Wih, const float* __restrict__ Whh,
    const float* __restrict__ Wm1, const float* __restrict__ Wm2,
    const float* __restrict__ Wo1, const float* __restrict__ Wo2,
    const float* __restrict__ smu, const float* __restrict__ sls,
    const float* __restrict__ noise, float* __restrict__ ws) {
  int idx = blockIdx.x * 256 + threadIdx.x;
  if (idx < 16384) { int j = idx >> 7, d = idx & 127; ws[OFF_WQT + d*128 + j] = Wq[idx]; return; }
  idx -= 16384;
  if (idx < 16384) { int j = idx >> 7, d = idx & 127; ws[OFF_WKT + d*128 + j] = Wk[idx]; return; }
  idx -= 16384;
  if (idx < 49152) { int j = idx >> 7, d = idx & 127; ws[OFF_WIHT + d*384 + j] = Wih[idx]; return; }
  idx -= 49152;
  if (idx < 49152) { int j = idx >> 7, d = idx & 127; ws[OFF_WHHT + d*384 + j] = Whh[idx]; return; }
  idx -= 49152;
  if (idx < 16384) { int j = idx >> 7, d = idx & 127; ws[OFF_WM1T + d*128 + j] = Wm1[idx]; return; }
  idx -= 16384;
  if (idx < 16384) { int j = idx >> 7, d = idx & 127; ws[OFF_WM2T + d*128 + j] = Wm2[idx]; return; }
  idx -= 16384;
  if (idx < 65536) { int j = idx >> 8, d = idx & 255; ws[OFF_WO1T + d*256 + j] = Wo1[idx]; return; }
  idx -= 65536;
  if (idx < 32768) { int j = idx >> 8, m = idx & 255; ws[OFF_WO2T + m*128 + j] = Wo2[idx]; return; }
  idx -= 32768;
  if (idx < 32768) { int c = idx & 255; ws[OFF_SLOTS + idx] = smu[c] + expf(sls[c]) * noise[idx]; return; }
  idx -= 32768;
  if (idx < 128) { ws[OFF_PI + idx] = 0.125f; }
}

// ---------------------------------------------------------------------------
// k = LN(inputs) @ Wk.T   (16 rows per block)
__global__ __launch_bounds__(256) void k_kernel(
    const float* __restrict__ xin, const float* __restrict__ g, const float* __restrict__ bb,
    const float* __restrict__ WkT, float* __restrict__ kout) {
  __shared__ float xs[16][128];
  __shared__ float2 red[16][16];
  __shared__ float mrow[16], srow[16];
  int t = threadIdx.x;
  int base = blockIdx.x * 2048;   // 16 rows * 128
  const float4* in4 = (const float4*)(xin + base);
  for (int f = t; f < 512; f += 256) {
    float4 v = in4[f];
    *(float4*)&xs[f >> 5][(f & 31) * 4] = v;
  }
  __syncthreads();
  {
    int row = t >> 4, l = t & 15;
    float s = 0.f, ss = 0.f;
    #pragma unroll
    for (int d = 0; d < 128; d += 16) { float v = xs[row][d + l]; s += v; ss = fmaf(v, v, ss); }
    red[row][l] = make_float2(s, ss);
  }
  __syncthreads();
  if (t < 16) {
    float s = 0.f, ss = 0.f;
    #pragma unroll
    for (int l = 0; l < 16; ++l) { float2 p = red[t][l]; s += p.x; ss += p.y; }
    float m = s * (1.0f/128.0f);
    float var = ss * (1.0f/128.0f) - m * m;
    mrow[t] = m;
    srow[t] = rsqrtf(var + 1e-5f);
  }
  __syncthreads();
  for (int f = t; f < 2048; f += 256) {
    int row = f >> 7, d = f & 127;
    xs[row][d] = (xs[row][d] - mrow[row]) * srow[row] * g[d] + bb[d];
  }
  __syncthreads();
  int j = t & 127, half = t >> 7;
  float acc[8] = {0,0,0,0,0,0,0,0};
  const int r0 = half * 8;
  #pragma unroll 4
  for (int d = 0; d < 128; ++d) {
    float w = WkT[d * 128 + j];
    #pragma unroll
    for (int r = 0; r < 8; ++r) acc[r] = fmaf(w, xs[r0 + r][d], acc[r]);
  }
  #pragma unroll
  for (int r = 0; r < 8; ++r) kout[base + (r0 + r) * 128 + j] = acc[r];
}

// ---------------------------------------------------------------------------
// S1: s = LN(slots); q_mu = mu_s@Wq.T; inv_var = exp(-2*(ls_s@Wq.T)); store mu_s
__global__ __launch_bounds__(256) void s1_kernel(
    const float* __restrict__ slots, const float* __restrict__ g, const float* __restrict__ bb,
    const float* __restrict__ WqT, float* __restrict__ mus, float* __restrict__ qmu,
    float* __restrict__ ivar) {
  __shared__ float sl[256];
  __shared__ float2 wr[4];
  int t = threadIdx.x, bi = blockIdx.x;
  float v = slots[bi * 256 + t];
  float s = v, ss = v * v;
  #pragma unroll
  for (int o = 32; o > 0; o >>= 1) { s += __shfl_down(s, o); ss += __shfl_down(ss, o); }
  if ((t & 63) == 0) wr[t >> 6] = make_float2(s, ss);
  __syncthreads();
  float fs  = wr[0].x + wr[1].x + wr[2].x + wr[3].x;
  float fss = wr[0].y + wr[1].y + wr[2].y + wr[3].y;
  float m   = fs * (1.0f/256.0f);
  float var = fss * (1.0f/256.0f) - m * m;
  float isr = rsqrtf(var + 1e-5f);
  float sn  = (v - m) * isr * g[t] + bb[t];
  sl[t] = sn;
  __syncthreads();
  if (t < 128) {
    float acc = 0.f;
    #pragma unroll 4
    for (int d = 0; d < 128; ++d) acc = fmaf(sl[d], WqT[d * 128 + t], acc);
    qmu[bi * 128 + t] = acc;
    mus[bi * 128 + t] = sn;
  } else {
    int jj = t - 128;
    float acc = 0.f;
    #pragma unroll 4
    for (int d = 0; d < 128; ++d) acc = fmaf(sl[128 + d], WqT[d * 128 + jj], acc);
    ivar[bi * 128 + jj] = expf(-2.0f * acc);
  }
}

// ---------------------------------------------------------------------------
// S2: per (b, 128-row n-chunk): dots -> gammas -> partial {sum g*k, sum g*k^2, sum g}
__global__ __launch_bounds__(1024) void s2_kernel(
    const float* __restrict__ kmat, const float* __restrict__ qmu,
    const float* __restrict__ ivar, const float* __restrict__ pi,
    float* __restrict__ wun, float* __restrict__ ws2, float* __restrict__ wden) {
  __shared__ float kc[128][132];
  __shared__ float qs[8 * 132];
  __shared__ float ivs[8 * 132];
  __shared__ float es[8 * 132];
  __shared__ float gam[128 * 12];
  __shared__ float recip[128];
  __shared__ float pis[8];
  int t = threadIdx.x;
  int chunk = blockIdx.x, b = blockIdx.y;
  if (t < 8) pis[t] = pi[b * 8 + t];
  { int i = t >> 7, d = t & 127;
    qs[i * 132 + d]  = qmu[b * 1024 + t];
    ivs[i * 132 + d] = ivar[b * 1024 + t]; }
  const float4* k4 = (const float4*)(kmat + (b * 2048 + chunk * 128) * 128);
  for (int f = t; f < 4096; f += 1024)
    *(float4*)&kc[f >> 5][(f & 31) * 4] = k4[f];
  __syncthreads();
  // phase 1: dots + e = (exp(-dots)+EPS)*pi   (thread -> (g = t&7, n = t>>3))
  {
    int gsl = t & 7, n = t >> 3;
    float acc = 0.f;
    const float* qrow = qs + gsl * 132;
    const float* irow = ivs + gsl * 132;
    const float* krow = &kc[n][0];
    #pragma unroll 4
    for (int dq = 0; dq < 32; ++dq) {
      float4 kv = *(const float4*)(krow + dq * 4);
      float4 qv = *(const float4*)(qrow + dq * 4);
      float4 iv = *(const float4*)(irow + dq * 4);
      float d0 = kv.x - qv.x, d1 = kv.y - qv.y, d2 = kv.z - qv.z, d3 = kv.w - qv.w;
      acc = fmaf(d0 * d0, iv.x, acc);
      acc = fmaf(d1 * d1, iv.y, acc);
      acc = fmaf(d2 * d2, iv.z, acc);
      acc = fmaf(d3 * d3, iv.w, acc);
    }
    es[gsl * 132 + n] = (expf(-acc) + EPS_) * pis[gsl];
  }
  __syncthreads();
  // recip over slots (gamma denominator per n)
  if (t < 128) {
    float ssum = 0.f;
    #pragma unroll
    for (int g2 = 0; g2 < 8; ++g2) ssum += es[g2 * 132 + t];
    recip[t] = 1.0f / ssum;
  }
  __syncthreads();
  { int i = t >> 7, n = t & 127;
    gam[n * 12 + i] = es[i * 132 + n] * recip[n]; }
  __syncthreads();
  // phase 2: per d accumulate over n for all 8 slots
  if (t < 128) {
    int d = t;
    float un[8] = {0,0,0,0,0,0,0,0};
    float s2[8] = {0,0,0,0,0,0,0,0};
    #pragma unroll 2
    for (int n = 0; n < 128; ++n) {
      float kk  = kc[n][d];
      float kk2 = kk * kk;
      float4 g0 = *(const float4*)&gam[n * 12];
      float4 g1 = *(const float4*)&gam[n * 12 + 4];
      un[0] = fmaf(g0.x, kk, un[0]); s2[0] = fmaf(g0.x, kk2, s2[0]);
      un[1] = fmaf(g0.y, kk, un[1]); s2[1] = fmaf(g0.y, kk2, s2[1]);
      un[2] = fmaf(g0.z, kk, un[2]); s2[2] = fmaf(g0.z, kk2, s2[2]);
      un[3] = fmaf(g0.w, kk, un[3]); s2[3] = fmaf(g0.w, kk2, s2[3]);
      un[4] = fmaf(g1.x, kk, un[4]); s2[4] = fmaf(g1.x, kk2, s2[4]);
      un[5] = fmaf(g1.y, kk, un[5]); s2[5] = fmaf(g1.y, kk2, s2[5]);
      un[6] = fmaf(g1.z, kk, un[6]); s2[6] = fmaf(g1.z, kk2, s2[6]);
      un[7] = fmaf(g1.w, kk, un[7]); s2[7] = fmaf(g1.w, kk2, s2[7]);
    }
    int pbase = ((b * 16 + chunk) * 8) * 128 + d;
    #pragma unroll
    for (int i = 0; i < 8; ++i) { wun[pbase + i * 128] = un[i]; ws2[pbase + i * 128] = s2[i]; }
  } else if (t < 136) {
    int i = t - 128;
    float dsum = 0.f;
    for (int n = 0; n < 128; ++n) dsum += gam[n * 12 + i];
    wden[(b * 16 + chunk) * 8 + i] = dsum;
  }
}

// ---------------------------------------------------------------------------
// S3: reduce partials, GRU, LN, MLP, upd_ls; write slots_new + pi_new
__global__ __launch_bounds__(128) void s3_kernel(
    const float* __restrict__ wun, const float* __restrict__ ws2, const float* __restrict__ wden,
    const float* __restrict__ mus,
    const float* __restrict__ WihT, const float* __restrict__ WhhT,
    const float* __restrict__ bih,  const float* __restrict__ bhh,
    const float* __restrict__ Wm1T, const float* __restrict__ bm1,
    const float* __restrict__ Wm2T, const float* __restrict__ bm2,
    const float* __restrict__ gmu,  const float* __restrict__ bmu,
    float* __restrict__ slots, float* __restrict__ pi) {
  int d = threadIdx.x, bi = blockIdx.x;
  int b = bi >> 3, i = bi & 7;
  float un = 0.f, s2v = 0.f, den = 0.f;
  #pragma unroll
  for (int c = 0; c < 16; ++c) {
    int po = ((b * 16 + c) * 8 + i) * 128 + d;
    un  += wun[po];
    s2v += ws2[po];
    den += wden[(b * 16 + c) * 8 + i];
  }
  __shared__ float xs[128], hs[128];
  float x = un / den;
  float hv_own = mus[bi * 128 + d];
  xs[d] = x; hs[d] = hv_own;
  __syncthreads();
  float a0=0,a1=0,a2=0,a3=0,a4=0,a5=0;
  #pragma unroll 2
  for (int dd = 0; dd < 128; ++dd) {
    float xv = xs[dd], hv = hs[dd];
    const float* wi = &WihT[dd * 384 + d];
    const float* wh = &WhhT[dd * 384 + d];
    a0 = fmaf(xv, wi[0],   a0);
    a1 = fmaf(xv, wi[128], a1);
    a2 = fmaf(xv, wi[256], a2);
    a3 = fmaf(hv, wh[0],   a3);
    a4 = fmaf(hv, wh[128], a4);
    a5 = fmaf(hv, wh[256], a5);
  }
  float ir = a0 + bih[d], iz = a1 + bih[128 + d], inn = a2 + bih[256 + d];
  float hr = a3 + bhh[d], hz = a4 + bhh[128 + d], hn  = a5 + bhh[256 + d];
  float r  = 1.0f / (1.0f + expf(-(ir + hr)));
  float z  = 1.0f / (1.0f + expf(-(iz + hz)));
  float nn = tanhf(inn + r * hn);
  float gru = (1.0f - z) * nn + z * hv_own;
  // LN over 128 (2 waves)
  float s = gru, ss = gru * gru;
  #pragma unroll
  for (int o = 32; o > 0; o >>= 1) { s += __shfl_down(s, o); ss += __shfl_down(ss, o); }
  __shared__ float2 wr2[2];
  if ((d & 63) == 0) wr2[d >> 6] = make_float2(s, ss);
  __syncthreads();
  float fs = wr2[0].x + wr2[1].x, fss = wr2[0].y + wr2[1].y;
  float mean = fs * (1.0f/128.0f);
  float var  = fss * (1.0f/128.0f) - mean * mean;
  float hln  = (gru - mean) * rsqrtf(var + 1e-5f) * gmu[d] + bmu[d];
  __shared__ float hl[128], m1s[128];
  hl[d] = hln;
  __syncthreads();
  float m1 = 0.f;
  #pragma unroll 4
  for (int dd = 0; dd < 128; ++dd) m1 = fmaf(hl[dd], Wm1T[dd * 128 + d], m1);
  m1 = fmaxf(m1 + bm1[d], 0.0f);
  m1s[d] = m1;
  __syncthreads();
  float m2 = 0.f;
  #pragma unroll 4
  for (int dd = 0; dd < 128; ++dd) m2 = fmaf(m1s[dd], Wm2T[dd * 128 + d], m2);
  float u = gru + m2 + bm2[d];
  // upd_ls = 0.5*log( sum_n attn*(k-u)^2 + EPS ) via expansion
  float val = (s2v - 2.0f * u * un + u * u * den) / den;
  float ls = 0.5f * logf(fmaxf(val, 0.0f) + EPS_);
  slots[bi * 256 + d]       = u;
  slots[bi * 256 + 128 + d] = ls;
  if (d == 0) pi[bi] = den;
}

// ---------------------------------------------------------------------------
// final output MLP: out = relu(slots@Wo1.T+b1)@Wo2.T+b2
__global__ __launch_bounds__(256) void out_kernel(
    const float* __restrict__ slots,
    const float* __restrict__ W1T, const float* __restrict__ b1,
    const float* __restrict__ W2T, const float* __restrict__ b2,
    float* __restrict__ out) {
  __shared__ float sl[256], hh[256];
  int t = threadIdx.x, bi = blockIdx.x;
  sl[t] = slots[bi * 256 + t];
  __syncthreads();
  float a = 0.f;
  #pragma unroll 4
  for (int dd = 0; dd < 256; ++dd) a = fmaf(sl[dd], W1T[dd * 256 + t], a);
  hh[t] = fmaxf(a + b1[t], 0.0f);
  __syncthreads();
  if (t < 128) {
    float o = 0.f;
    #pragma unroll 4
    for (int m = 0; m < 256; ++m) o = fmaf(hh[m], W2T[m * 128 + t], o);
    out[bi * 128 + t] = o + b2[t];
  }
}

// ---------------------------------------------------------------------------
extern "C" void kernel_launch(void* const* d_in, const int* in_sizes, int n_in,
                              void* d_out, int out_size, void* d_ws, size_t ws_size,
                              hipStream_t stream) {
  const float* inputs = (const float*)d_in[0];
  const float* noise  = (const float*)d_in[1];
  const float* smu    = (const float*)d_in[2];
  const float* sls    = (const float*)d_in[3];
  const float* Wq     = (const float*)d_in[4];
  const float* Wk     = (const float*)d_in[5];
  const float* Wih    = (const float*)d_in[6];
  const float* Whh    = (const float*)d_in[7];
  const float* bih    = (const float*)d_in[8];
  const float* bhh    = (const float*)d_in[9];
  const float* Wm1    = (const float*)d_in[10];
  const float* bm1    = (const float*)d_in[11];
  const float* Wm2    = (const float*)d_in[12];
  const float* bm2    = (const float*)d_in[13];
  const float* gin    = (const float*)d_in[14];
  const float* bin    = (const float*)d_in[15];
  const float* gsl    = (const float*)d_in[16];
  const float* bsl    = (const float*)d_in[17];
  const float* gmu    = (const float*)d_in[18];
  const float* bmu    = (const float*)d_in[19];
  const float* Wo1    = (const float*)d_in[20];
  const float* bo1    = (const float*)d_in[21];
  const float* Wo2    = (const float*)d_in[22];
  const float* bo2    = (const float*)d_in[23];

  float* ws    = (float*)d_ws;
  float* kbuf  = ws + OFF_K;
  float* WqT   = ws + OFF_WQT;
  float* WkT   = ws + OFF_WKT;
  float* WihT  = ws + OFF_WIHT;
  float* WhhT  = ws + OFF_WHHT;
  float* Wm1T  = ws + OFF_WM1T;
  float* Wm2T  = ws + OFF_WM2T;
  float* Wo1T  = ws + OFF_WO1T;
  float* Wo2T  = ws + OFF_WO2T;
  float* slots = ws + OFF_SLOTS;
  float* pibuf = ws + OFF_PI;
  float* mus   = ws + OFF_MUS;
  float* qmu   = ws + OFF_QMU;
  float* ivar  = ws + OFF_IVAR;
  float* wun   = ws + OFF_UN;
  float* ws2   = ws + OFF_S2;
  float* wden  = ws + OFF_DEN;

  // init + transposes: 295040 elements
  hipLaunchKernelGGL(init_kernel, dim3(1153), dim3(256), 0, stream,
                     Wq, Wk, Wih, Whh, Wm1, Wm2, Wo1, Wo2, smu, sls, noise, ws);
  // k = LN(inputs) @ Wk.T : 32768 rows / 16 per block
  hipLaunchKernelGGL(k_kernel, dim3(2048), dim3(256), 0, stream,
                     inputs, gin, bin, WkT, kbuf);
  for (int s = 0; s < 4; ++s) {
    hipLaunchKernelGGL(s1_kernel, dim3(128), dim3(256), 0, stream,
                       slots, gsl, bsl, WqT, mus, qmu, ivar);
    hipLaunchKernelGGL(s2_kernel, dim3(16, 16), dim3(1024), 0, stream,
                       kbuf, qmu, ivar, pibuf, wun, ws2, wden);
    hipLaunchKernelGGL(s3_kernel, dim3(128), dim3(128), 0, stream,
                       wun, ws2, wden, mus, WihT, WhhT, bih, bhh,
                       Wm1T, bm1, Wm2T, bm2, gmu, bmu, slots, pibuf);
  }
  hipLaunchKernelGGL(out_kernel, dim3(128), dim3(256), 0, stream,
                     slots, Wo1T, bo1, Wo2T, bo2, (float*)d_out);
}

// Round 2
// 168.385 us; speedup vs baseline: 1.8802x; 1.8802x over previous
//
#include <hip/hip_runtime.h>

#define EPS_ 1e-8f

// sizes: B=16, N=2048, D=128, NS=8, H=128, steps=4
// ws offsets (floats)
constexpr int OFF_K     = 0;                       // 16*2048*128 = 4194304
constexpr int OFF_WQT   = 4194304;                 // 16384
constexpr int OFF_WKT   = OFF_WQT  + 16384;
constexpr int OFF_WIHT  = OFF_WKT  + 16384;        // 49152
constexpr int OFF_WHHT  = OFF_WIHT + 49152;        // 49152
constexpr int OFF_WM1T  = OFF_WHHT + 49152;        // 16384
constexpr int OFF_WM2T  = OFF_WM1T + 16384;        // 16384
constexpr int OFF_WO1T  = OFF_WM2T + 16384;        // 65536
constexpr int OFF_WO2T  = OFF_WO1T + 65536;        // 32768
constexpr int OFF_SLOTS = OFF_WO2T + 32768;        // 32768
constexpr int OFF_PI    = OFF_SLOTS+ 32768;        // 128
constexpr int OFF_MUS   = OFF_PI   + 128;          // 16384
constexpr int OFF_QMU   = OFF_MUS  + 16384;        // 16384
constexpr int OFF_IVAR  = OFF_QMU  + 16384;        // 16384
constexpr int OFF_UN    = OFF_IVAR + 16384;        // 16*16*8*128 = 262144
constexpr int OFF_S2    = OFF_UN   + 262144;       // 262144
constexpr int OFF_DEN   = OFF_S2   + 262144;       // 2048

// ---------------------------------------------------------------------------
// init: transpose all weights into ws, init slots, pi
__global__ __launch_bounds__(256) void init_kernel(
    const float* __restrict__ Wq,  const float* __restrict__ Wk,
    const float* __restrict__ Wih, const float* __restrict__ Whh,
    const float* __restrict__ Wm1, const float* __restrict__ Wm2,
    const float* __restrict__ Wo1, const float* __restrict__ Wo2,
    const float* __restrict__ smu, const float* __restrict__ sls,
    const float* __restrict__ noise, float* __restrict__ ws) {
  int idx = blockIdx.x * 256 + threadIdx.x;
  if (idx < 16384) { int j = idx >> 7, d = idx & 127; ws[OFF_WQT + d*128 + j] = Wq[idx]; return; }
  idx -= 16384;
  if (idx < 16384) { int j = idx >> 7, d = idx & 127; ws[OFF_WKT + d*128 + j] = Wk[idx]; return; }
  idx -= 16384;
  if (idx < 49152) { int j = idx >> 7, d = idx & 127; ws[OFF_WIHT + d*384 + j] = Wih[idx]; return; }
  idx -= 49152;
  if (idx < 49152) { int j = idx >> 7, d = idx & 127; ws[OFF_WHHT + d*384 + j] = Whh[idx]; return; }
  idx -= 49152;
  if (idx < 16384) { int j = idx >> 7, d = idx & 127; ws[OFF_WM1T + d*128 + j] = Wm1[idx]; return; }
  idx -= 16384;
  if (idx < 16384) { int j = idx >> 7, d = idx & 127; ws[OFF_WM2T + d*128 + j] = Wm2[idx]; return; }
  idx -= 16384;
  if (idx < 65536) { int j = idx >> 8, d = idx & 255; ws[OFF_WO1T + d*256 + j] = Wo1[idx]; return; }
  idx -= 65536;
  if (idx < 32768) { int j = idx >> 8, m = idx & 255; ws[OFF_WO2T + m*128 + j] = Wo2[idx]; return; }
  idx -= 32768;
  if (idx < 32768) { int c = idx & 255; ws[OFF_SLOTS + idx] = smu[c] + expf(sls[c]) * noise[idx]; return; }
  idx -= 32768;
  if (idx < 128) { ws[OFF_PI + idx] = 0.125f; }
}

// ---------------------------------------------------------------------------
// k = LN(inputs) @ Wk.T   (16 rows per block)
__global__ __launch_bounds__(256) void k_kernel(
    const float* __restrict__ xin, const float* __restrict__ g, const float* __restrict__ bb,
    const float* __restrict__ WkT, float* __restrict__ kout) {
  __shared__ float xs[16][128];
  __shared__ float2 red[16][16];
  __shared__ float mrow[16], srow[16];
  int t = threadIdx.x;
  int base = blockIdx.x * 2048;   // 16 rows * 128
  const float4* in4 = (const float4*)(xin + base);
  for (int f = t; f < 512; f += 256) {
    float4 v = in4[f];
    *(float4*)&xs[f >> 5][(f & 31) * 4] = v;
  }
  __syncthreads();
  {
    int row = t >> 4, l = t & 15;
    float s = 0.f, ss = 0.f;
    #pragma unroll
    for (int d = 0; d < 128; d += 16) { float v = xs[row][d + l]; s += v; ss = fmaf(v, v, ss); }
    red[row][l] = make_float2(s, ss);
  }
  __syncthreads();
  if (t < 16) {
    float s = 0.f, ss = 0.f;
    #pragma unroll
    for (int l = 0; l < 16; ++l) { float2 p = red[t][l]; s += p.x; ss += p.y; }
    float m = s * (1.0f/128.0f);
    float var = ss * (1.0f/128.0f) - m * m;
    mrow[t] = m;
    srow[t] = rsqrtf(var + 1e-5f);
  }
  __syncthreads();
  for (int f = t; f < 2048; f += 256) {
    int row = f >> 7, d = f & 127;
    xs[row][d] = (xs[row][d] - mrow[row]) * srow[row] * g[d] + bb[d];
  }
  __syncthreads();
  int j = t & 127, half = t >> 7;
  float acc[8] = {0,0,0,0,0,0,0,0};
  const int r0 = half * 8;
  #pragma unroll 4
  for (int d = 0; d < 128; ++d) {
    float w = WkT[d * 128 + j];
    #pragma unroll
    for (int r = 0; r < 8; ++r) acc[r] = fmaf(w, xs[r0 + r][d], acc[r]);
  }
  #pragma unroll
  for (int r = 0; r < 8; ++r) kout[base + (r0 + r) * 128 + j] = acc[r];
}

// ---------------------------------------------------------------------------
// S1 standalone (first iteration only)
__global__ __launch_bounds__(256) void s1_kernel(
    const float* __restrict__ slots, const float* __restrict__ g, const float* __restrict__ bb,
    const float* __restrict__ WqT, float* __restrict__ mus, float* __restrict__ qmu,
    float* __restrict__ ivar) {
  __shared__ float sl[256];
  __shared__ float2 wr[4];
  int t = threadIdx.x, bi = blockIdx.x;
  float v = slots[bi * 256 + t];
  float s = v, ss = v * v;
  #pragma unroll
  for (int o = 32; o > 0; o >>= 1) { s += __shfl_down(s, o); ss += __shfl_down(ss, o); }
  if ((t & 63) == 0) wr[t >> 6] = make_float2(s, ss);
  __syncthreads();
  float fs  = wr[0].x + wr[1].x + wr[2].x + wr[3].x;
  float fss = wr[0].y + wr[1].y + wr[2].y + wr[3].y;
  float m   = fs * (1.0f/256.0f);
  float var = fss * (1.0f/256.0f) - m * m;
  float isr = rsqrtf(var + 1e-5f);
  float sn  = (v - m) * isr * g[t] + bb[t];
  sl[t] = sn;
  __syncthreads();
  if (t < 128) {
    float acc = 0.f;
    #pragma unroll 4
    for (int d = 0; d < 128; ++d) acc = fmaf(sl[d], WqT[d * 128 + t], acc);
    qmu[bi * 128 + t] = acc;
    mus[bi * 128 + t] = sn;
  } else {
    int jj = t - 128;
    float acc = 0.f;
    #pragma unroll 4
    for (int d = 0; d < 128; ++d) acc = fmaf(sl[128 + d], WqT[d * 128 + jj], acc);
    ivar[bi * 128 + jj] = expf(-2.0f * acc);
  }
}

// ---------------------------------------------------------------------------
// S2: per (b, 128-row n-chunk): dots -> gammas -> partial {sum g*k, sum g*k^2, sum g}
__global__ __launch_bounds__(1024) void s2_kernel(
    const float* __restrict__ kmat, const float* __restrict__ qmu,
    const float* __restrict__ ivar, const float* __restrict__ pi,
    float* __restrict__ wun, float* __restrict__ ws2, float* __restrict__ wden) {
  __shared__ float kc[128][132];
  __shared__ float qs[8 * 132];
  __shared__ float ivs[8 * 132];
  __shared__ float es[8 * 132];
  __shared__ float gam[128 * 12];
  __shared__ float recip[128];
  __shared__ float pis[8];
  __shared__ float pU[4][8][128];
  __shared__ float pS[4][8][128];
  __shared__ float pd[8][8];
  int t = threadIdx.x;
  int chunk = blockIdx.x, b = blockIdx.y;
  if (t < 8) pis[t] = pi[b * 8 + t];
  { int ii = t >> 7, dd = t & 127;
    qs[ii * 132 + dd]  = qmu[b * 1024 + t];
    ivs[ii * 132 + dd] = ivar[b * 1024 + t]; }
  const float4* k4 = (const float4*)(kmat + (b * 2048 + chunk * 128) * 128);
  for (int f = t; f < 4096; f += 1024)
    *(float4*)&kc[f >> 5][(f & 31) * 4] = k4[f];
  __syncthreads();
  // phase 1: dots + e = (exp(-dots)+EPS)*pi ; 2 n's per thread (512 active)
  if (t < 512) {
    int gsl = t & 7, n0 = (t >> 3) << 1;
    float acc0 = 0.f, acc1 = 0.f;
    const float* qrow = qs + gsl * 132;
    const float* irow = ivs + gsl * 132;
    const float* k0r  = &kc[n0][0];
    const float* k1r  = &kc[n0 + 1][0];
    #pragma unroll 4
    for (int dq = 0; dq < 32; ++dq) {
      float4 qv = *(const float4*)(qrow + dq * 4);
      float4 iv = *(const float4*)(irow + dq * 4);
      float4 k0 = *(const float4*)(k0r + dq * 4);
      float4 k1 = *(const float4*)(k1r + dq * 4);
      float e;
      e = k0.x - qv.x; acc0 = fmaf(e * e, iv.x, acc0);
      e = k0.y - qv.y; acc0 = fmaf(e * e, iv.y, acc0);
      e = k0.z - qv.z; acc0 = fmaf(e * e, iv.z, acc0);
      e = k0.w - qv.w; acc0 = fmaf(e * e, iv.w, acc0);
      e = k1.x - qv.x; acc1 = fmaf(e * e, iv.x, acc1);
      e = k1.y - qv.y; acc1 = fmaf(e * e, iv.y, acc1);
      e = k1.z - qv.z; acc1 = fmaf(e * e, iv.z, acc1);
      e = k1.w - qv.w; acc1 = fmaf(e * e, iv.w, acc1);
    }
    es[gsl * 132 + n0]     = (expf(-acc0) + EPS_) * pis[gsl];
    es[gsl * 132 + n0 + 1] = (expf(-acc1) + EPS_) * pis[gsl];
  }
  __syncthreads();
  if (t < 128) {
    float ssum = 0.f;
    #pragma unroll
    for (int g2 = 0; g2 < 8; ++g2) ssum += es[g2 * 132 + t];
    recip[t] = 1.0f / ssum;
  }
  __syncthreads();
  { int ii = t >> 7, n = t & 127;
    gam[n * 12 + ii] = es[ii * 132 + n] * recip[n]; }
  __syncthreads();
  // phase 2: 4 n-groups of 32, each accumulating all 8 slots; plus den partials
  if (t < 512) {
    int grp = t >> 7, dd = t & 127;
    float un[8] = {0,0,0,0,0,0,0,0};
    float s2[8] = {0,0,0,0,0,0,0,0};
    #pragma unroll 2
    for (int n = grp * 32; n < grp * 32 + 32; ++n) {
      float kk  = kc[n][dd];
      float kk2 = kk * kk;
      float4 g0 = *(const float4*)&gam[n * 12];
      float4 g1 = *(const float4*)&gam[n * 12 + 4];
      un[0] = fmaf(g0.x, kk, un[0]); s2[0] = fmaf(g0.x, kk2, s2[0]);
      un[1] = fmaf(g0.y, kk, un[1]); s2[1] = fmaf(g0.y, kk2, s2[1]);
      un[2] = fmaf(g0.z, kk, un[2]); s2[2] = fmaf(g0.z, kk2, s2[2]);
      un[3] = fmaf(g0.w, kk, un[3]); s2[3] = fmaf(g0.w, kk2, s2[3]);
      un[4] = fmaf(g1.x, kk, un[4]); s2[4] = fmaf(g1.x, kk2, s2[4]);
      un[5] = fmaf(g1.y, kk, un[5]); s2[5] = fmaf(g1.y, kk2, s2[5]);
      un[6] = fmaf(g1.z, kk, un[6]); s2[6] = fmaf(g1.z, kk2, s2[6]);
      un[7] = fmaf(g1.w, kk, un[7]); s2[7] = fmaf(g1.w, kk2, s2[7]);
    }
    #pragma unroll
    for (int ii = 0; ii < 8; ++ii) { pU[grp][ii][dd] = un[ii]; pS[grp][ii][dd] = s2[ii]; }
  } else if (t < 576) {
    int ii = (t - 512) & 7, sub = (t - 512) >> 3;
    float dsum = 0.f;
    for (int n = sub * 16; n < sub * 16 + 16; ++n) dsum += gam[n * 12 + ii];
    pd[sub][ii] = dsum;
  }
  __syncthreads();
  { int ii = t >> 7, dd = t & 127;
    int pbase = ((b * 16 + chunk) * 8 + ii) * 128 + dd;
    wun[pbase] = pU[0][ii][dd] + pU[1][ii][dd] + pU[2][ii][dd] + pU[3][ii][dd];
    ws2[pbase] = pS[0][ii][dd] + pS[1][ii][dd] + pS[2][ii][dd] + pS[3][ii][dd]; }
  if (t < 8) {
    float s = 0.f;
    #pragma unroll
    for (int sub = 0; sub < 8; ++sub) s += pd[sub][t];
    wden[(b * 16 + chunk) * 8 + t] = s;
  }
}

// ---------------------------------------------------------------------------
// S3 fused: partial-reduce + GRU + LN + MLP + upd_ls + slots/pi write,
// then either next-iter S1 (slot LN + q/ivar) or the final output MLP.
// 512 threads, one block per (b,slot) row. Split-K (4-way) everywhere.
__global__ __launch_bounds__(512) void s3_kernel(
    const float* __restrict__ wun, const float* __restrict__ ws2, const float* __restrict__ wden,
    const float* __restrict__ WihT, const float* __restrict__ WhhT,
    const float* __restrict__ bih,  const float* __restrict__ bhh,
    const float* __restrict__ Wm1T, const float* __restrict__ bm1,
    const float* __restrict__ Wm2T, const float* __restrict__ bm2,
    const float* __restrict__ gmu,  const float* __restrict__ bmu,
    float* __restrict__ slots, float* __restrict__ pi,
    int do_s1,
    const float* __restrict__ gs, const float* __restrict__ bs,
    const float* __restrict__ WqT,
    float* __restrict__ mus, float* __restrict__ qmu, float* __restrict__ ivar,
    const float* __restrict__ Wo1T, const float* __restrict__ bo1,
    const float* __restrict__ Wo2T, const float* __restrict__ bo2,
    float* __restrict__ out) {
  int t = threadIdx.x, bi = blockIdx.x;
  int d = t & 127, q = t >> 7;      // q in [0,4)
  int b = bi >> 3, i = bi & 7;
  __shared__ float redU[4][128], redS[4][128];
  __shared__ float dred[16];
  __shared__ float xs[128], hs[128];
  __shared__ float gacc[4][6][128];
  __shared__ float ga[6][128];
  __shared__ float grus[128], hl[128], m1s[128];
  __shared__ float macc[4][128];
  __shared__ float2 wr2[2];
  __shared__ float uarr[256];
  // ---- phase A: reduce partials
  float unp = 0.f, s2p = 0.f;
  #pragma unroll
  for (int c = q * 4; c < q * 4 + 4; ++c) {
    int po = ((b * 16 + c) * 8 + i) * 128 + d;
    unp += wun[po]; s2p += ws2[po];
  }
  redU[q][d] = unp; redS[q][d] = s2p;
  if (t < 16) dred[t] = wden[(b * 16 + t) * 8 + i];
  if (q == 1) hs[d] = mus[bi * 128 + d];
  __syncthreads();
  float den = 0.f;
  #pragma unroll
  for (int c = 0; c < 16; ++c) den += dred[c];
  float un  = redU[0][d] + redU[1][d] + redU[2][d] + redU[3][d];
  float s2v = redS[0][d] + redS[1][d] + redS[2][d] + redS[3][d];
  if (q == 0) xs[d] = un / den;
  __syncthreads();
  // ---- phase B: GRU matvecs, split-K over q
  {
    float a0 = 0, a1 = 0, a2 = 0, a3 = 0, a4 = 0, a5 = 0;
    #pragma unroll 4
    for (int dd = q * 32; dd < q * 32 + 32; ++dd) {
      float xv = xs[dd], hv = hs[dd];
      const float* wi = &WihT[dd * 384 + d];
      const float* wh = &WhhT[dd * 384 + d];
      a0 = fmaf(xv, wi[0],   a0);
      a1 = fmaf(xv, wi[128], a1);
      a2 = fmaf(xv, wi[256], a2);
      a3 = fmaf(hv, wh[0],   a3);
      a4 = fmaf(hv, wh[128], a4);
      a5 = fmaf(hv, wh[256], a5);
    }
    gacc[q][0][d] = a0; gacc[q][1][d] = a1; gacc[q][2][d] = a2;
    gacc[q][3][d] = a3; gacc[q][4][d] = a4; gacc[q][5][d] = a5;
  }
  __syncthreads();
  for (int f = t; f < 768; f += 512) {
    int j = f >> 7, dd = f & 127;
    ga[j][dd] = gacc[0][j][dd] + gacc[1][j][dd] + gacc[2][j][dd] + gacc[3][j][dd];
  }
  __syncthreads();
  // ---- GRU nonlinearity + LN (first 2 waves)
  float gru = 0.f;
  if (q == 0) {
    float ir = ga[0][d] + bih[d], iz = ga[1][d] + bih[128 + d], inn = ga[2][d] + bih[256 + d];
    float hr = ga[3][d] + bhh[d], hz = ga[4][d] + bhh[128 + d], hn  = ga[5][d] + bhh[256 + d];
    float r  = 1.0f / (1.0f + expf(-(ir + hr)));
    float z  = 1.0f / (1.0f + expf(-(iz + hz)));
    float nn = tanhf(inn + r * hn);
    gru = (1.0f - z) * nn + z * hs[d];
    grus[d] = gru;
    float s = gru, ssq = gru * gru;
    #pragma unroll
    for (int o = 32; o > 0; o >>= 1) { s += __shfl_down(s, o); ssq += __shfl_down(ssq, o); }
    if ((d & 63) == 0) wr2[d >> 6] = make_float2(s, ssq);
  }
  __syncthreads();
  if (q == 0) {
    float fs = wr2[0].x + wr2[1].x, fss = wr2[0].y + wr2[1].y;
    float mean = fs * (1.0f/128.0f);
    float var  = fss * (1.0f/128.0f) - mean * mean;
    hl[d] = (gru - mean) * rsqrtf(var + 1e-5f) * gmu[d] + bmu[d];
  }
  __syncthreads();
  // ---- MLP (mu branch), split-K
  {
    float m1p = 0.f;
    #pragma unroll 4
    for (int dd = q * 32; dd < q * 32 + 32; ++dd)
      m1p = fmaf(hl[dd], Wm1T[dd * 128 + d], m1p);
    macc[q][d] = m1p;
  }
  __syncthreads();
  if (q == 0) m1s[d] = fmaxf(macc[0][d] + macc[1][d] + macc[2][d] + macc[3][d] + bm1[d], 0.f);
  __syncthreads();
  {
    float m2p = 0.f;
    #pragma unroll 4
    for (int dd = q * 32; dd < q * 32 + 32; ++dd)
      m2p = fmaf(m1s[dd], Wm2T[dd * 128 + d], m2p);
    macc[q][d] = m2p;
  }
  __syncthreads();
  if (q == 0) {
    float u = grus[d] + macc[0][d] + macc[1][d] + macc[2][d] + macc[3][d] + bm2[d];
    float val = (s2v - 2.0f * u * un + u * u * den) / den;
    float ls = 0.5f * logf(fmaxf(val, 0.0f) + EPS_);
    slots[bi * 256 + d]       = u;
    slots[bi * 256 + 128 + d] = ls;
    uarr[d] = u; uarr[128 + d] = ls;
    if (d == 0) pi[bi] = den;
  }
  __syncthreads();
  if (do_s1) {
    // ---- fused S1 for next iteration: LN over 256 + q_mu / inv_var matvecs
    __shared__ float2 wr4[4];
    __shared__ float sln[256];
    __shared__ float qacc[2][2][128];
    if (t < 256) {
      float v = uarr[t];
      float s = v, ssq = v * v;
      #pragma unroll
      for (int o = 32; o > 0; o >>= 1) { s += __shfl_down(s, o); ssq += __shfl_down(ssq, o); }
      if ((t & 63) == 0) wr4[t >> 6] = make_float2(s, ssq);
    }
    __syncthreads();
    if (t < 256) {
      float fs  = wr4[0].x + wr4[1].x + wr4[2].x + wr4[3].x;
      float fss = wr4[0].y + wr4[1].y + wr4[2].y + wr4[3].y;
      float m   = fs * (1.0f/256.0f);
      float var = fss * (1.0f/256.0f) - m * m;
      sln[t] = (uarr[t] - m) * rsqrtf(var + 1e-5f) * gs[t] + bs[t];
    }
    __syncthreads();
    {
      int h2 = t >> 8, qq = (t >> 7) & 1, d2 = t & 127;
      const float* src = sln + h2 * 128;
      float acc = 0.f;
      #pragma unroll 4
      for (int dd = qq * 64; dd < qq * 64 + 64; ++dd)
        acc = fmaf(src[dd], WqT[dd * 128 + d2], acc);
      qacc[h2][qq][d2] = acc;
    }
    __syncthreads();
    if (t < 128) {
      qmu[bi * 128 + t] = qacc[0][0][t] + qacc[0][1][t];
      mus[bi * 128 + t] = sln[t];
    } else if (t < 256) {
      int dd2 = t - 128;
      ivar[bi * 128 + dd2] = expf(-2.0f * (qacc[1][0][dd2] + qacc[1][1][dd2]));
    }
  } else {
    // ---- fused output MLP: out = relu(slots@Wo1.T+b1)@Wo2.T+b2
    __shared__ float oacc[2][256];
    __shared__ float hh[256];
    {
      int o = t & 255, qq = t >> 8;
      float acc = 0.f;
      #pragma unroll 4
      for (int dd = qq * 128; dd < qq * 128 + 128; ++dd)
        acc = fmaf(uarr[dd], Wo1T[dd * 256 + o], acc);
      oacc[qq][o] = acc;
    }
    __syncthreads();
    if (t < 256) hh[t] = fmaxf(oacc[0][t] + oacc[1][t] + bo1[t], 0.f);
    __syncthreads();
    {
      int o2 = t & 127, q4 = t >> 7;
      float acc2 = 0.f;
      #pragma unroll 4
      for (int dd = q4 * 64; dd < q4 * 64 + 64; ++dd)
        acc2 = fmaf(hh[dd], Wo2T[dd * 128 + o2], acc2);
      macc[q4][o2] = acc2;
    }
    __syncthreads();
    if (t < 128) out[bi * 128 + t] = macc[0][t] + macc[1][t] + macc[2][t] + macc[3][t] + bo2[t];
  }
}

// ---------------------------------------------------------------------------
extern "C" void kernel_launch(void* const* d_in, const int* in_sizes, int n_in,
                              void* d_out, int out_size, void* d_ws, size_t ws_size,
                              hipStream_t stream) {
  const float* inputs = (const float*)d_in[0];
  const float* noise  = (const float*)d_in[1];
  const float* smu    = (const float*)d_in[2];
  const float* sls    = (const float*)d_in[3];
  const float* Wq     = (const float*)d_in[4];
  const float* Wk     = (const float*)d_in[5];
  const float* Wih    = (const float*)d_in[6];
  const float* Whh    = (const float*)d_in[7];
  const float* bih    = (const float*)d_in[8];
  const float* bhh    = (const float*)d_in[9];
  const float* Wm1    = (const float*)d_in[10];
  const float* bm1    = (const float*)d_in[11];
  const float* Wm2    = (const float*)d_in[12];
  const float* bm2    = (const float*)d_in[13];
  const float* gin    = (const float*)d_in[14];
  const float* bin    = (const float*)d_in[15];
  const float* gsl    = (const float*)d_in[16];
  const float* bsl    = (const float*)d_in[17];
  const float* gmu    = (const float*)d_in[18];
  const float* bmu    = (const float*)d_in[19];
  const float* Wo1    = (const float*)d_in[20];
  const float* bo1    = (const float*)d_in[21];
  const float* Wo2    = (const float*)d_in[22];
  const float* bo2    = (const float*)d_in[23];

  float* ws    = (float*)d_ws;
  float* kbuf  = ws + OFF_K;
  float* WqT   = ws + OFF_WQT;
  float* WkT   = ws + OFF_WKT;
  float* WihT  = ws + OFF_WIHT;
  float* WhhT  = ws + OFF_WHHT;
  float* Wm1T  = ws + OFF_WM1T;
  float* Wm2T  = ws + OFF_WM2T;
  float* Wo1T  = ws + OFF_WO1T;
  float* Wo2T  = ws + OFF_WO2T;
  float* slots = ws + OFF_SLOTS;
  float* pibuf = ws + OFF_PI;
  float* mus   = ws + OFF_MUS;
  float* qmu   = ws + OFF_QMU;
  float* ivar  = ws + OFF_IVAR;
  float* wun   = ws + OFF_UN;
  float* ws2   = ws + OFF_S2;
  float* wden  = ws + OFF_DEN;

  hipLaunchKernelGGL(init_kernel, dim3(1153), dim3(256), 0, stream,
                     Wq, Wk, Wih, Whh, Wm1, Wm2, Wo1, Wo2, smu, sls, noise, ws);
  hipLaunchKernelGGL(k_kernel, dim3(2048), dim3(256), 0, stream,
                     inputs, gin, bin, WkT, kbuf);
  hipLaunchKernelGGL(s1_kernel, dim3(128), dim3(256), 0, stream,
                     slots, gsl, bsl, WqT, mus, qmu, ivar);
  for (int s = 0; s < 4; ++s) {
    hipLaunchKernelGGL(s2_kernel, dim3(16, 16), dim3(1024), 0, stream,
                       kbuf, qmu, ivar, pibuf, wun, ws2, wden);
    hipLaunchKernelGGL(s3_kernel, dim3(128), dim3(512), 0, stream,
                       wun, ws2, wden, WihT, WhhT, bih, bhh,
                       Wm1T, bm1, Wm2T, bm2, gmu, bmu, slots, pibuf,
                       (s < 3) ? 1 : 0, gsl, bsl, WqT, mus, qmu, ivar,
                       Wo1T, bo1, Wo2T, bo2, (float*)d_out);
  }
}